// Round 2
// baseline (685.113 us; speedup 1.0000x reference)
//
#include <hip/hip_runtime.h>

#define Bn 8
#define Cn 3
#define Sn 1024
#define DIMn 768
#define Hn 3
#define HDn 256
#define BCHn 72

typedef __bf16 bf16x8 __attribute__((ext_vector_type(8)));
typedef float f32x4 __attribute__((ext_vector_type(4)));
typedef float f32x16 __attribute__((ext_vector_type(16)));
typedef unsigned short u16x8 __attribute__((ext_vector_type(8)));
typedef unsigned short u16x4 __attribute__((ext_vector_type(4)));

static __device__ __forceinline__ unsigned short f2bf(float f){
  unsigned u = __builtin_bit_cast(unsigned, f);
  u += 0x7fffu + ((u >> 16) & 1u);
  return (unsigned short)(u >> 16);
}
static __device__ __forceinline__ u16x4 cvt4(float4 v){
  u16x4 r = { f2bf(v.x), f2bf(v.y), f2bf(v.z), f2bf(v.w) };
  return r;
}
static __device__ __forceinline__ bf16x8 ld8(const unsigned short* p){
  return __builtin_bit_cast(bf16x8, *(const u16x8*)p);
}
static __device__ __forceinline__ float fexp2(float x){
#if __has_builtin(__builtin_amdgcn_exp2f)
  return __builtin_amdgcn_exp2f(x);
#else
  return exp2f(x);
#endif
}

// ---------------- Kernel 1: K and V^T projections ----------------
// job 0: K[t][e]  = sum_d X[t,d] Wk[e,d] + bk[e]   (A=X rows, B=Wk rows)
// job 1: Vt[e][t] = sum_d Wv[e,d] X[t,d] + bv[e]   (A=Wv rows, B=X rows)
// Block computes a full 128x256 C tile; epilogue transposes through LDS for
// 16B-coalesced global stores.
__global__ __launch_bounds__(256, 2) void projkv(
    const float* __restrict__ x,
    const float* __restrict__ Wk, const float* __restrict__ bk,
    const float* __restrict__ Wv, const float* __restrict__ bv,
    unsigned short* __restrict__ Kw, unsigned short* __restrict__ Vt)
{
  __shared__ alignas(16) unsigned short SM2[16896]; // 33,792 B
  unsigned short* Al = SM2;          // [128][40]
  unsigned short* Bl = SM2 + 5120;   // [256][40]
  unsigned short* T  = SM2;          // epilogue: [64][264]

  const int tid = threadIdx.x, lane = tid & 63, wave = tid >> 6;
  const int l15 = lane & 15, quad = lane >> 4, kr = quad * 8;
  const int bch = blockIdx.z;
  const int h = bch % Hn, c = (bch / Hn) % Cn, b = bch / (Hn*Cn);
  const long xbase = ((long)(b*Cn + c) * Sn) * DIMn + h * HDn;
  const int job = blockIdx.y;
  const float *aP, *bP, *biasP;
  int aStr, bStr, mbase, nbase, ldc;
  if (job == 0){
    aP = x + xbase;        aStr = DIMn; mbase = blockIdx.x * 128;
    bP = Wk + h*HDn*HDn;   bStr = HDn;  nbase = 0;
    biasP = bk + h*HDn;    ldc = HDn;
  } else {
    aP = Wv + h*HDn*HDn;   aStr = HDn;  mbase = (blockIdx.x & 1) * 128;
    bP = x + xbase;        bStr = DIMn; nbase = (blockIdx.x >> 1) * 256;
    biasP = bv + h*HDn;    ldc = Sn;
  }
  unsigned short* outP = (job == 0 ? Kw : Vt) + (long)bch * Sn * HDn;

  f32x4 acc[4][8] = {};
  const int wm = (wave & 1) * 64, wn = (wave >> 1) * 128;

  for (int ks = 0; ks < 8; ++ks){
    const int k0 = ks * 32;
    #pragma unroll
    for (int i = 0; i < 4; ++i){
      int id = tid + i*256, row = id >> 3, f4 = (id & 7) * 4;
      float4 va = *(const float4*)(aP + (long)(mbase + row) * aStr + k0 + f4);
      *(u16x4*)&Al[row*40 + f4] = cvt4(va);
    }
    #pragma unroll
    for (int i = 0; i < 8; ++i){
      int id = tid + i*256, row = id >> 3, f4 = (id & 7) * 4;
      float4 vb = *(const float4*)(bP + (long)(nbase + row) * bStr + k0 + f4);
      *(u16x4*)&Bl[row*40 + f4] = cvt4(vb);
    }
    __syncthreads();
    bf16x8 af[4], bfr[8];
    #pragma unroll
    for (int t = 0; t < 4; ++t) af[t] = ld8(&Al[(wm + t*16 + l15)*40 + kr]);
    #pragma unroll
    for (int u = 0; u < 8; ++u) bfr[u] = ld8(&Bl[(wn + u*16 + l15)*40 + kr]);
    #pragma unroll
    for (int t = 0; t < 4; ++t)
      #pragma unroll
      for (int u = 0; u < 8; ++u)
        acc[t][u] = __builtin_amdgcn_mfma_f32_16x16x32_bf16(af[t], bfr[u], acc[t][u], 0, 0, 0);
    __syncthreads();
  }

  // Epilogue: dump 64-row halves into LDS (bf16) then store coalesced.
  #pragma unroll
  for (int half = 0; half < 2; ++half){
    if ((wave & 1) == half){
      #pragma unroll
      for (int t = 0; t < 4; ++t){
        #pragma unroll
        for (int u = 0; u < 8; ++u){
          const int col = wn + u*16 + l15;
          const float cbias = job ? 0.0f : biasP[col];
          #pragma unroll
          for (int r = 0; r < 4; ++r){
            const int lrow = t*16 + quad*4 + r;
            float v = acc[t][u][r] + (job ? biasP[mbase + half*64 + lrow] : cbias);
            T[lrow*264 + col] = f2bf(v);
          }
        }
      }
    }
    __syncthreads();
    #pragma unroll
    for (int i = 0; i < 8; ++i){
      int id = tid + i*256, row = id >> 5, c8 = (id & 31) * 8;
      int grow = mbase + half*64 + row;
      *(u16x8*)(outP + (long)grow * ldc + nbase + c8) = *(const u16x8*)&T[row*264 + c8];
    }
    __syncthreads();
  }
}

// ---------------- Kernel 2: fused Q projection + attention ----------------
// Block = one (bch, 128-row Q tile), 4 waves, 32 Q rows per wave, 32x32x16 MFMA.
// No online softmax (scores bounded): p = exp2(q'.k), q' = (xWq+bq)*log2e/16.
// Row sums via an extra all-ones V column tile (o[8]).
__global__ __launch_bounds__(256, 2) void attn(
    const float* __restrict__ x,
    const float* __restrict__ Wq, const float* __restrict__ bq,
    const unsigned short* __restrict__ Kw, const unsigned short* __restrict__ Vt,
    float* __restrict__ out)
{
  __shared__ alignas(16) unsigned short SM[37632]; // 75,264 B
  // Phase A: XA [128][40] @0 ; WL [256][40] @5120 ; TB [128][72] @0
  // Phase B: KL [64][264] @0 ; PL [128][72] @0 (aliases consumed KL) ; VL [288][72] @16896
  unsigned short* XA = SM;
  unsigned short* WL = SM + 5120;
  unsigned short* TB = SM;
  unsigned short* KL = SM;
  unsigned short* PL = SM;
  unsigned short* VL = SM + 16896;

  const int tid = threadIdx.x, lane = tid & 63, wave = tid >> 6;
  const int l31 = lane & 31, hi = lane >> 5;
  const int bid = blockIdx.x;
  // XCD swizzle: the 8 q-tiles of one bch share bid&7
  const int idx0 = bid >> 3;
  const int bch = (idx0 >> 3) * 8 + (bid & 7);
  const int qt  = idx0 & 7;
  const int h = bch % Hn, c = (bch / Hn) % Cn, b = bch / (Hn*Cn);
  const long xbase = ((long)(b*Cn + c) * Sn) * DIMn + h * HDn;
  const int q0 = qt * 128;
  const int wq = wave * 32;

  // ones-column V tile (VL rows 256..287; region untouched by phase A)
  for (int i = tid; i < 2048; i += 256){
    int j = i >> 6, t = i & 63;
    VL[(256 + j)*72 + t] = (j == 0) ? (unsigned short)0x3F80 : (unsigned short)0;
  }

  // ---- Phase A: Q' = (X@Wq^T + bq) * (log2e/16), kept as 32x32 A-fragments ----
  f32x16 qa[8] = {};
  const float* Wqh = Wq + h*HDn*HDn;
  for (int ks = 0; ks < 8; ++ks){
    const int k0 = ks * 32;
    #pragma unroll
    for (int i = 0; i < 4; ++i){
      int id = tid + i*256, row = id >> 3, f4 = (id & 7) * 4;
      float4 v = *(const float4*)(x + xbase + (long)(q0 + row) * DIMn + k0 + f4);
      *(u16x4*)&XA[row*40 + f4] = cvt4(v);
    }
    #pragma unroll
    for (int i = 0; i < 8; ++i){
      int id = tid + i*256, row = id >> 3, f4 = (id & 7) * 4;
      float4 v = *(const float4*)(Wqh + row*HDn + k0 + f4);
      *(u16x4*)&WL[row*40 + f4] = cvt4(v);
    }
    __syncthreads();
    #pragma unroll
    for (int kk = 0; kk < 2; ++kk){
      bf16x8 a = ld8(&XA[(wq + l31)*40 + kk*16 + hi*8]);
      #pragma unroll
      for (int et = 0; et < 8; ++et){
        bf16x8 bb = ld8(&WL[(et*32 + l31)*40 + kk*16 + hi*8]);
        qa[et] = __builtin_amdgcn_mfma_f32_32x32x16_bf16(a, bb, qa[et], 0, 0, 0);
      }
    }
    __syncthreads();
  }

  // C-layout -> A-layout via LDS, 64-col groups
  const float s2 = 0.09016844136545405f; // log2(e)/16
  bf16x8 qf[16];
  #pragma unroll
  for (int g = 0; g < 4; ++g){
    #pragma unroll
    for (int e2 = 0; e2 < 2; ++e2){
      const int et = g*2 + e2;
      const float bias = bq[h*HDn + et*32 + l31];
      #pragma unroll
      for (int reg = 0; reg < 16; ++reg){
        const int crow = (reg & 3) + 8*(reg >> 2) + 4*hi;
        TB[(wq + crow)*72 + e2*32 + l31] = f2bf((qa[et][reg] + bias) * s2);
      }
    }
    __syncthreads();
    #pragma unroll
    for (int j = 0; j < 4; ++j)
      qf[g*4 + j] = ld8(&TB[(wq + l31)*72 + j*16 + hi*8]);
    __syncthreads();
  }

  // ---- Phase B: loop over 64-wide KV chunks ----
  f32x16 o[9] = {};
  const unsigned short* Kb = Kw + (long)bch * Sn * HDn;
  const unsigned short* Vb = Vt + (long)bch * Sn * HDn;

  for (int jt = 0; jt < 16; ++jt){
    const int t0 = jt * 64;
    #pragma unroll
    for (int i = 0; i < 8; ++i){
      int id = tid + i*256, row = id >> 5, c8 = (id & 31) * 8;
      *(u16x8*)&KL[row*264 + c8] = *(const u16x8*)(Kb + (long)(t0 + row)*HDn + c8);
    }
    #pragma unroll
    for (int i = 0; i < 8; ++i){
      int id = tid + i*256, e = id >> 3, c8 = (id & 7) * 8;
      *(u16x8*)&VL[e*72 + c8] = *(const u16x8*)(Vb + (long)e*Sn + t0 + c8);
    }
    __syncthreads();

    f32x16 s0 = {}, s1 = {};
    #pragma unroll
    for (int kk = 0; kk < 16; ++kk){
      bf16x8 b0 = ld8(&KL[l31*264 + kk*16 + hi*8]);
      bf16x8 b1 = ld8(&KL[(32 + l31)*264 + kk*16 + hi*8]);
      s0 = __builtin_amdgcn_mfma_f32_32x32x16_bf16(qf[kk], b0, s0, 0, 0, 0);
      s1 = __builtin_amdgcn_mfma_f32_32x32x16_bf16(qf[kk], b1, s1, 0, 0, 0);
    }
    __syncthreads();  // all KL reads done before PL (alias) is written

    #pragma unroll
    for (int reg = 0; reg < 16; ++reg){
      const int crow = (reg & 3) + 8*(reg >> 2) + 4*hi;
      PL[(wq + crow)*72 + l31]      = f2bf(fexp2(s0[reg]));
      PL[(wq + crow)*72 + 32 + l31] = f2bf(fexp2(s1[reg]));
    }
    // PV: each wave reads only its own P rows -> same-wave DS ordering suffices
    #pragma unroll
    for (int kk2 = 0; kk2 < 4; ++kk2){
      bf16x8 pf = ld8(&PL[(wq + l31)*72 + kk2*16 + hi*8]);
      #pragma unroll
      for (int nt = 0; nt < 9; ++nt){
        bf16x8 vf = ld8(&VL[(nt*32 + l31)*72 + kk2*16 + hi*8]);
        o[nt] = __builtin_amdgcn_mfma_f32_32x32x16_bf16(pf, vf, o[nt], 0, 0, 0);
      }
    }
    __syncthreads();  // PL/VL consumed before next staging
  }

  // ---- Epilogue: l = o[8] (ones-column), same C-layout rows as o ----
  #pragma unroll
  for (int reg = 0; reg < 16; ++reg){
    const int crow = (reg & 3) + 8*(reg >> 2) + 4*hi;
    const float l = __shfl(o[8][reg], (lane & 32)); // col 0 of this half's rows
    const float inv = 1.0f / l;
    const int grow = q0 + wq + crow;
    float* op = out + ((long)(b*Sn + grow)*Cn + c)*DIMn + h*HDn;
    #pragma unroll
    for (int nt = 0; nt < 8; ++nt)
      op[nt*32 + l31] = o[nt][reg] * inv;
  }
}

extern "C" void kernel_launch(void* const* d_in, const int* in_sizes, int n_in,
                              void* d_out, int out_size, void* d_ws, size_t ws_size,
                              hipStream_t stream) {
  const float* x  = (const float*)d_in[0];
  const float* Wq = (const float*)d_in[1];
  const float* bq = (const float*)d_in[2];
  const float* Wk = (const float*)d_in[3];
  const float* bk = (const float*)d_in[4];
  const float* Wv = (const float*)d_in[5];
  const float* bv = (const float*)d_in[6];
  float* out = (float*)d_out;
  unsigned short* Kw = (unsigned short*)d_ws;                 // [72][1024][256] bf16
  unsigned short* Vt = Kw + (size_t)BCHn * Sn * HDn;          // [72][256][1024] bf16

  dim3 g1(8, 2, BCHn);
  projkv<<<g1, 256, 0, stream>>>(x, Wk, bk, Wv, bv, Kw, Vt);
  attn<<<dim3(BCHn * 8), 256, 0, stream>>>(x, Wq, bq, Kw, Vt, out);
}

// Round 3
// 333.765 us; speedup vs baseline: 2.0527x; 2.0527x over previous
//
#include <hip/hip_runtime.h>

#define Bn 8
#define Cn 3
#define Sn 1024
#define DIMn 768
#define Hn 3
#define HDn 256
#define BCHn 72
#define SnHD (Sn*HDn)

typedef __bf16 bf16x8 __attribute__((ext_vector_type(8)));
typedef float f32x4 __attribute__((ext_vector_type(4)));
typedef unsigned short u16x8 __attribute__((ext_vector_type(8)));
typedef unsigned short u16x4 __attribute__((ext_vector_type(4)));

static __device__ __forceinline__ unsigned short f2bf(float f){
  unsigned u = __builtin_bit_cast(unsigned, f);
  u += 0x7fffu + ((u >> 16) & 1u);
  return (unsigned short)(u >> 16);
}
static __device__ __forceinline__ u16x4 cvt4(float4 v){
  u16x4 r = { f2bf(v.x), f2bf(v.y), f2bf(v.z), f2bf(v.w) };
  return r;
}
static __device__ __forceinline__ bf16x8 ld8(const unsigned short* p){
  return __builtin_bit_cast(bf16x8, *(const u16x8*)p);
}
static __device__ __forceinline__ float fexp2(float x){
#if __has_builtin(__builtin_amdgcn_exp2f)
  return __builtin_amdgcn_exp2f(x);
#else
  return exp2f(x);
#endif
}

#if __has_builtin(__builtin_amdgcn_global_load_lds)
#define HAVE_ASYNC 1
static __device__ __forceinline__ void async16(const void* g, void* l){
  __builtin_amdgcn_global_load_lds((const __attribute__((address_space(1))) void*)g,
                                   (__attribute__((address_space(3))) void*)l, 16, 0, 0);
}
#else
#define HAVE_ASYNC 0
#endif

// ---------------- Kernel 0: W -> bf16 (Wq pre-scaled by log2e/16) ----------------
__global__ __launch_bounds__(256) void wprep(
    const float* __restrict__ Wq, const float* __restrict__ Wk, const float* __restrict__ Wv,
    unsigned short* __restrict__ Wb)
{
  const int which = blockIdx.z, h = blockIdx.y;
  const float* src = which == 0 ? Wq : (which == 1 ? Wk : Wv);
  const float scale = (which == 0) ? 0.09016844136545405f : 1.0f; // log2(e)/16
  const int off = blockIdx.x*1024 + threadIdx.x*4;
  float4 v = *(const float4*)(src + (long)h*65536 + off);
  v.x *= scale; v.y *= scale; v.z *= scale; v.w *= scale;
  *(u16x4*)(Wb + (long)(which*Hn + h)*65536 + off) = cvt4(v);
}

// ---------------- Kernel 1: fused K and V^T projections ----------------
// Block = (bch, 64 t-rows). x-tile staged once serves K (A-frag) and Vt (B-frag).
// K[t][e] = x.Wk^T + bk ; Vt[e][t] = Wv.x^T + bv. Coalesced stores via LDS transpose.
__global__ __launch_bounds__(256, 2) void projkv(
    const float* __restrict__ x, const unsigned short* __restrict__ Wb,
    const float* __restrict__ bk, const float* __restrict__ bv,
    unsigned short* __restrict__ Kw, unsigned short* __restrict__ Vt)
{
  __shared__ alignas(16) unsigned short SM[23040]; // 46,080 B
  unsigned short* XA  = SM;          // [64][40]
  unsigned short* WkL = SM + 2560;   // [256][40]
  unsigned short* WvL = SM + 12800;  // [256][40]
  unsigned short* TK  = SM;          // epilogue [64][264]
  unsigned short* TV  = SM;          // epilogue [256][72]

  const int tid = threadIdx.x, lane = tid & 63, wave = tid >> 6;
  const int l15 = lane & 15, quad = lane >> 4;
  const int bch = blockIdx.y;
  const int h = bch % Hn, c = (bch / Hn) % Cn, b = bch / (Hn*Cn);
  const int tb = blockIdx.x * 64;
  const long xb_ = ((long)(b*Cn + c)*Sn + tb)*DIMn + h*HDn;
  const unsigned short* Wkb = Wb + (long)(1*Hn + h)*65536;
  const unsigned short* Wvb = Wb + (long)(2*Hn + h)*65536;

  float4 xr[2]; u16x8 wk[4], wv[4];
  auto loadg = [&](int ks){
    const int k0 = ks*32;
    #pragma unroll
    for (int i = 0; i < 2; ++i){
      int id = tid + i*256;
      xr[i] = *(const float4*)(x + xb_ + (long)(id>>3)*DIMn + k0 + (id&7)*4);
    }
    #pragma unroll
    for (int i = 0; i < 4; ++i){
      int id = tid + i*256;
      wk[i] = *(const u16x8*)(Wkb + (id>>2)*HDn + k0 + (id&3)*8);
      wv[i] = *(const u16x8*)(Wvb + (id>>2)*HDn + k0 + (id&3)*8);
    }
  };
  loadg(0);

  f32x4 Ka[16] = {}; f32x4 Va[4][4] = {};
  for (int ks = 0; ks < 8; ++ks){
    #pragma unroll
    for (int i = 0; i < 2; ++i){
      int id = tid + i*256;
      *(u16x4*)&XA[(id>>3)*40 + (id&7)*4] = cvt4(xr[i]);
    }
    #pragma unroll
    for (int i = 0; i < 4; ++i){
      int id = tid + i*256;
      *(u16x8*)&WkL[(id>>2)*40 + (id&3)*8] = wk[i];
      *(u16x8*)&WvL[(id>>2)*40 + (id&3)*8] = wv[i];
    }
    __syncthreads();
    if (ks < 7) loadg(ks + 1);
    bf16x8 af = ld8(&XA[(wave*16 + l15)*40 + quad*8]);
    #pragma unroll
    for (int nt = 0; nt < 16; ++nt){
      bf16x8 bw = ld8(&WkL[(nt*16 + l15)*40 + quad*8]);
      Ka[nt] = __builtin_amdgcn_mfma_f32_16x16x32_bf16(af, bw, Ka[nt], 0, 0, 0);
    }
    bf16x8 avf[4], bxf[4];
    #pragma unroll
    for (int j = 0; j < 4; ++j) avf[j] = ld8(&WvL[((wave*4 + j)*16 + l15)*40 + quad*8]);
    #pragma unroll
    for (int n = 0; n < 4; ++n) bxf[n] = ld8(&XA[(n*16 + l15)*40 + quad*8]);
    #pragma unroll
    for (int j = 0; j < 4; ++j)
      #pragma unroll
      for (int n = 0; n < 4; ++n)
        Va[j][n] = __builtin_amdgcn_mfma_f32_16x16x32_bf16(avf[j], bxf[n], Va[j][n], 0, 0, 0);
    __syncthreads();
  }

  const float* bkh = bk + h*HDn;
  const float* bvh = bv + h*HDn;
  // K epilogue
  #pragma unroll
  for (int nt = 0; nt < 16; ++nt){
    const float bb = bkh[nt*16 + l15];
    #pragma unroll
    for (int r = 0; r < 4; ++r)
      TK[(wave*16 + quad*4 + r)*264 + nt*16 + l15] = f2bf(Ka[nt][r] + bb);
  }
  __syncthreads();
  unsigned short* Kg = Kw + (long)bch*SnHD + (long)tb*HDn;
  #pragma unroll
  for (int i = 0; i < 8; ++i){
    int id = tid + i*256, row = id>>5, c8 = (id&31)*8;
    *(u16x8*)(Kg + row*HDn + c8) = *(const u16x8*)&TK[row*264 + c8];
  }
  __syncthreads();
  // Vt epilogue
  #pragma unroll
  for (int j = 0; j < 4; ++j){
    #pragma unroll
    for (int n = 0; n < 4; ++n){
      #pragma unroll
      for (int r = 0; r < 4; ++r){
        const int er = wave*64 + j*16 + quad*4 + r;
        TV[er*72 + n*16 + l15] = f2bf(Va[j][n][r] + bvh[er]);
      }
    }
  }
  __syncthreads();
  unsigned short* Vg = Vt + (long)bch*SnHD + tb;
  #pragma unroll
  for (int i = 0; i < 8; ++i){
    int id = tid + i*256, row = id>>3, c8 = (id&7)*8;
    *(u16x8*)(Vg + (long)row*Sn + c8) = *(const u16x8*)&TV[row*72 + c8];
  }
}

// ---------------- Kernel 2: fused Q projection + attention ----------------
// Block = (bch, 64 Q-rows), 4 waves x 16 rows, 16x16x32 MFMA.
// p = exp2(q'.k), q' = x.(Wq*log2e/16)^T + bq*log2e/16 (scale folded at wprep).
// Row-sum l via all-ones 17th V tile. K async-staged into XOR-swizzled LDS.
__global__ __launch_bounds__(256, 3) void attn(
    const float* __restrict__ x, const unsigned short* __restrict__ Wb,
    const float* __restrict__ bq,
    const unsigned short* __restrict__ Kw, const unsigned short* __restrict__ Vt,
    float* __restrict__ out)
{
  __shared__ alignas(16) unsigned short SM[21632]; // 43,264 B
  unsigned short* XA = SM;           // phase A [64][40]
  unsigned short* WL = SM + 2560;    // phase A [256][40]
  unsigned short* KL = SM;           // phase B [32][256] XOR-swizzled
  unsigned short* VL = SM + 8192;    // phase B [272][40] (rows 256..271 = ones tile)
  unsigned short* PL = SM + 19072;   // [4][16][40] per-wave

  const int tid = threadIdx.x, lane = tid & 63, wave = tid >> 6;
  const int l15 = lane & 15, quad = lane >> 4;
  const int bid = blockIdx.x;
  const int idx0 = bid >> 3;
  const int bch = (idx0 >> 4)*8 + (bid & 7);   // 8 q-tiles of a bch share bid&7 (XCD)
  const int qt  = idx0 & 15;
  const int h = bch % Hn, c = (bch / Hn) % Cn, b = bch / (Hn*Cn);
  const int q0 = qt * 64;
  const long xb_ = ((long)(b*Cn + c)*Sn + q0)*DIMn + h*HDn;
  const unsigned short* Wqb = Wb + (long)h*65536;

  // ---- Phase A: Q' as A-fragments in registers ----
  float4 xr[2]; u16x8 wr[4];
  auto loadgA = [&](int ks){
    const int k0 = ks*32;
    #pragma unroll
    for (int i = 0; i < 2; ++i){
      int id = tid + i*256;
      xr[i] = *(const float4*)(x + xb_ + (long)(id>>3)*DIMn + k0 + (id&7)*4);
    }
    #pragma unroll
    for (int i = 0; i < 4; ++i){
      int id = tid + i*256;
      wr[i] = *(const u16x8*)(Wqb + (id>>2)*HDn + k0 + (id&3)*8);
    }
  };
  loadgA(0);
  f32x4 qa[16] = {};
  for (int ks = 0; ks < 8; ++ks){
    #pragma unroll
    for (int i = 0; i < 2; ++i){
      int id = tid + i*256;
      *(u16x4*)&XA[(id>>3)*40 + (id&7)*4] = cvt4(xr[i]);
    }
    #pragma unroll
    for (int i = 0; i < 4; ++i){
      int id = tid + i*256;
      *(u16x8*)&WL[(id>>2)*40 + (id&3)*8] = wr[i];
    }
    __syncthreads();
    if (ks < 7) loadgA(ks + 1);
    bf16x8 af = ld8(&XA[(wave*16 + l15)*40 + quad*8]);
    #pragma unroll
    for (int nt = 0; nt < 16; ++nt){
      bf16x8 bw = ld8(&WL[(nt*16 + l15)*40 + quad*8]);
      qa[nt] = __builtin_amdgcn_mfma_f32_16x16x32_bf16(af, bw, qa[nt], 0, 0, 0);
    }
    __syncthreads();
  }

  const unsigned short* Kb = Kw + (long)bch*SnHD;
  const unsigned short* Vb = Vt + (long)bch*SnHD;

#if HAVE_ASYNC
  // issue async K staging for chunk jt into swizzled KL (safe: XA/WL dead)
  auto issueK = [&](int jt){
    const int t0 = jt*32;
    #pragma unroll
    for (int i = 0; i < 4; ++i){
      const int S = (wave*4 + i)*64 + lane;
      const int row = S >> 5, pos = S & 31, ch = pos ^ (row & 15);
      async16(Kb + (long)(t0 + row)*HDn + ch*8, (char*)KL + (wave*4 + i)*1024);
    }
  };
  issueK(0);
#else
  u16x8 kr_[4];
  auto loadK = [&](int jt){
    const int t0 = jt*32;
    #pragma unroll
    for (int i = 0; i < 4; ++i){
      const int S = (wave*4 + i)*64 + lane;
      const int row = S >> 5, pos = S & 31, ch = pos ^ (row & 15);
      kr_[i] = *(const u16x8*)(Kb + (long)(t0 + row)*HDn + ch*8);
    }
  };
  loadK(0);
#endif

  // Q C-layout -> A-layout via per-wave LDS buffer; fold scaled bias
  unsigned short* Pw = PL + wave*640;
  const float s2 = 0.09016844136545405f;
  bf16x8 qf[8];
  #pragma unroll
  for (int g = 0; g < 8; ++g){
    #pragma unroll
    for (int e2 = 0; e2 < 2; ++e2){
      const int nt = g*2 + e2;
      const float bias = bq[h*HDn + nt*16 + l15] * s2;
      #pragma unroll
      for (int r = 0; r < 4; ++r)
        Pw[(quad*4 + r)*40 + e2*16 + l15] = f2bf(qa[nt][r] + bias);
    }
    qf[g] = ld8(&Pw[l15*40 + quad*8]);
  }

  // ones tile init (VL rows 256..271, cols 0..31) — phase A LDS is dead here
  if (tid < 128){
    const int row = 256 + (tid >> 3), c4 = (tid & 7)*4;
    const unsigned short vv = (row == 256) ? (unsigned short)0x3F80 : (unsigned short)0;
    u16x4 z = { vv, vv, vv, vv };
    *(u16x4*)&VL[row*40 + c4] = z;
  }

  u16x8 vr[4];
  auto loadV = [&](int jt){
    const int t0 = jt*32;
    #pragma unroll
    for (int i = 0; i < 4; ++i){
      int id = tid + i*256;
      vr[i] = *(const u16x8*)(Vb + (long)(id>>2)*Sn + t0 + (id&3)*8);
    }
  };
  loadV(0);

  // ---- Phase B: 32 chunks of 32 keys ----
  f32x4 o[17] = {};
  for (int jt = 0; jt < 32; ++jt){
    #pragma unroll
    for (int i = 0; i < 4; ++i){
      int id = tid + i*256;
      *(u16x8*)&VL[(id>>2)*40 + (id&3)*8] = vr[i];
    }
#if !HAVE_ASYNC
    #pragma unroll
    for (int i = 0; i < 4; ++i){
      const int S = (wave*4 + i)*64 + lane;
      *(u16x8*)&KL[S*8] = kr_[i];
    }
#endif
    __syncthreads();   // drains async K(jt), V visible
    if (jt < 31){
      loadV(jt + 1);
#if !HAVE_ASYNC
      loadK(jt + 1);
#endif
    }
    // QK^T: two 16-row K tiles
    f32x4 s0 = {}, s1 = {};
    #pragma unroll
    for (int kk = 0; kk < 8; ++kk){
      const int pc = 4*kk + quad;
      bf16x8 b0 = ld8(&KL[l15*256 + (pc ^ l15)*8]);
      bf16x8 b1 = ld8(&KL[(16 + l15)*256 + (pc ^ l15)*8]);
      s0 = __builtin_amdgcn_mfma_f32_16x16x32_bf16(qf[kk], b0, s0, 0, 0, 0);
      s1 = __builtin_amdgcn_mfma_f32_16x16x32_bf16(qf[kk], b1, s1, 0, 0, 0);
    }
    // P = exp2(S), C-layout -> A-layout via per-wave buffer (in-wave DS order)
    #pragma unroll
    for (int r = 0; r < 4; ++r){
      Pw[(quad*4 + r)*40 + l15]      = f2bf(fexp2(s0[r]));
      Pw[(quad*4 + r)*40 + 16 + l15] = f2bf(fexp2(s1[r]));
    }
    bf16x8 pf = ld8(&Pw[l15*40 + quad*8]);
    #pragma unroll
    for (int nt = 0; nt < 17; ++nt){
      bf16x8 vf = ld8(&VL[(nt*16 + l15)*40 + quad*8]);
      o[nt] = __builtin_amdgcn_mfma_f32_16x16x32_bf16(pf, vf, o[nt], 0, 0, 0);
    }
    __syncthreads();   // all KL/VL reads done
#if HAVE_ASYNC
    if (jt < 31) issueK(jt + 1);  // in flight across next iter's V-write + barrier
#endif
  }

  // ---- Epilogue: l = ones-column tile o[16] ----
  #pragma unroll
  for (int r = 0; r < 4; ++r){
    const float l = __shfl(o[16][r], lane & 48);  // col 0 of own quad's rows
    const float inv = 1.0f / l;
    const int grow = q0 + wave*16 + quad*4 + r;
    float* op = out + ((long)(b*Sn + grow)*Cn + c)*DIMn + h*HDn;
    #pragma unroll
    for (int nt = 0; nt < 16; ++nt)
      op[nt*16 + l15] = o[nt][r] * inv;
  }
}

extern "C" void kernel_launch(void* const* d_in, const int* in_sizes, int n_in,
                              void* d_out, int out_size, void* d_ws, size_t ws_size,
                              hipStream_t stream) {
  const float* x  = (const float*)d_in[0];
  const float* Wq = (const float*)d_in[1];
  const float* bq = (const float*)d_in[2];
  const float* Wk = (const float*)d_in[3];
  const float* bk = (const float*)d_in[4];
  const float* Wv = (const float*)d_in[5];
  const float* bv = (const float*)d_in[6];
  float* out = (float*)d_out;
  unsigned short* Kw = (unsigned short*)d_ws;              // [72][1024][256] bf16
  unsigned short* Vt = Kw + (size_t)BCHn * SnHD;           // [72][256][1024] bf16
  unsigned short* Wb = Vt + (size_t)BCHn * SnHD;           // [3][3][256][256] bf16

  wprep<<<dim3(64, Hn, 3), 256, 0, stream>>>(Wq, Wk, Wv, Wb);
  projkv<<<dim3(16, BCHn), 256, 0, stream>>>(x, Wb, bk, bv, Kw, Vt);
  attn<<<dim3(BCHn * 16), 256, 0, stream>>>(x, Wb, bq, Kw, Vt, out);
}